// Round 6
// baseline (417.246 us; speedup 1.0000x reference)
//
#include <hip/hip_runtime.h>
#include <hip/hip_bf16.h>

#define B_ 4
#define S_ 4096
#define D_ 1024
#define E_ 8
#define F_ 2048
#define TK_ 512

typedef unsigned short u16;
typedef unsigned int u32;
typedef u16 u16x4 __attribute__((ext_vector_type(4)));
typedef u16 u16x8 __attribute__((ext_vector_type(8)));
typedef short s16x8 __attribute__((ext_vector_type(8)));
typedef float f32x4 __attribute__((ext_vector_type(4)));

__device__ __forceinline__ u16 f2bf(float f) {
  u32 u = __builtin_bit_cast(u32, f);
  u32 r = (u + 0x7fffu + ((u >> 16) & 1u)) >> 16;
  return (u16)r;
}
__device__ __forceinline__ float b2f(u16 h) {
  return __builtin_bit_cast(float, ((u32)h) << 16);
}
__device__ __forceinline__ void gload16(const u16* g, const u16* l) {
  __builtin_amdgcn_global_load_lds((const __attribute__((address_space(1))) void*)g,
                                   (__attribute__((address_space(3))) void*)l, 16, 0, 0);
}
__device__ __forceinline__ f32x4 mfma_bf16(s16x8 a, s16x8 b, f32x4 c) {
  return __builtin_amdgcn_mfma_f32_16x16x32_bf16(a, b, c, 0, 0, 0);
}

// ---------------- fused: router logits + x->bf16 + zero(results) ----------------
__global__ __launch_bounds__(256) void rc_kernel(const float* __restrict__ x,
                                                 const float* __restrict__ Wr,
                                                 float* __restrict__ logits,
                                                 u16* __restrict__ xb,
                                                 float* __restrict__ results) {
  __shared__ float wr[D_ * E_];
  for (int i = threadIdx.x; i < D_ * E_; i += 256) wr[i] = Wr[i];
  __syncthreads();
  int lane = threadIdx.x & 63;
  int wid = threadIdx.x >> 6;
  int token = blockIdx.x * 4 + wid;
  const float* xr = x + (size_t)token * D_;
  u16* xo = xb + (size_t)token * D_;
  float* ro = results + (size_t)token * D_;
  float acc[E_];
#pragma unroll
  for (int e = 0; e < E_; ++e) acc[e] = 0.f;
#pragma unroll
  for (int q = 0; q < 4; ++q) {
    int d0 = q * 256 + lane * 4;
    float4 v = *(const float4*)(xr + d0);
    u16x4 st;
    st[0] = f2bf(v.x); st[1] = f2bf(v.y); st[2] = f2bf(v.z); st[3] = f2bf(v.w);
    *(u16x4*)(xo + d0) = st;
    *(float4*)(ro + d0) = make_float4(0.f, 0.f, 0.f, 0.f);
    float xv[4] = {v.x, v.y, v.z, v.w};
    const float* w0 = &wr[d0 * E_];
#pragma unroll
    for (int j = 0; j < 4; ++j) {
#pragma unroll
      for (int e = 0; e < E_; ++e) acc[e] += xv[j] * w0[j * E_ + e];
    }
  }
#pragma unroll
  for (int e = 0; e < E_; ++e) {
#pragma unroll
    for (int off = 32; off; off >>= 1) acc[e] += __shfl_down(acc[e], off);
  }
  if (lane == 0) {
    float4 o0 = make_float4(acc[0], acc[1], acc[2], acc[3]);
    float4 o1 = make_float4(acc[4], acc[5], acc[6], acc[7]);
    *(float4*)(logits + (size_t)token * E_) = o0;
    *(float4*)(logits + (size_t)token * E_ + 4) = o1;
  }
}

// ---------------- top-k per (b,e): exact 3-level radix-histogram select ----------------
__device__ __forceinline__ void suffix_scan(u32* h, int n, int tid) {
  for (int d = 1; d < n; d <<= 1) {
    u32 v[2];
    int c = 0;
    for (int i = tid; i < n; i += 1024) v[c++] = (i + d < n) ? h[i + d] : 0;
    __syncthreads();
    c = 0;
    for (int i = tid; i < n; i += 1024) h[i] += v[c++];
    __syncthreads();
  }
}

__global__ __launch_bounds__(1024) void topk_kernel(const float* __restrict__ logits,
                                                    int* __restrict__ idx,
                                                    float* __restrict__ wts) {
  int be = blockIdx.x, b = be >> 3, e = be & 7;
  __shared__ u32 keys[S_];
  __shared__ u32 hist[2048];
  __shared__ u32 tcnt[1024];
  __shared__ u32 sb, sneed, scnt;
  int tid = threadIdx.x;
  const float* lg = logits + (size_t)b * S_ * E_;
  for (int s = tid; s < S_; s += 1024) {
    float4 l0 = *(const float4*)(lg + (size_t)s * E_);
    float4 l1 = *(const float4*)(lg + (size_t)s * E_ + 4);
    float la[8] = {l0.x, l0.y, l0.z, l0.w, l1.x, l1.y, l1.z, l1.w};
    float mx = la[0];
#pragma unroll
    for (int t = 1; t < 8; ++t) mx = fmaxf(mx, la[t]);
    float sum = 0.f;
#pragma unroll
    for (int t = 0; t < 8; ++t) sum += expf(la[t] - mx);
    float p = expf(la[e] - mx) / sum;
    keys[s] = __builtin_bit_cast(u32, p);
  }
  if (tid == 0) scnt = 0;

  hist[tid] = 0; hist[tid + 1024] = 0;
  __syncthreads();
  for (int s = tid; s < S_; s += 1024) atomicAdd(&hist[keys[s] >> 21], 1u);
  __syncthreads();
  suffix_scan(hist, 2048, tid);
  for (int i = tid; i < 2048; i += 1024) {
    u32 nxt = (i + 1 < 2048) ? hist[i + 1] : 0;
    if (hist[i] >= (u32)TK_ && nxt < (u32)TK_) { sb = (u32)i; sneed = TK_ - nxt; }
  }
  __syncthreads();
  u32 b1 = sb, need1 = sneed;
  __syncthreads();

  hist[tid] = 0; hist[tid + 1024] = 0;
  __syncthreads();
  for (int s = tid; s < S_; s += 1024)
    if ((keys[s] >> 21) == b1) atomicAdd(&hist[(keys[s] >> 10) & 2047u], 1u);
  __syncthreads();
  suffix_scan(hist, 2048, tid);
  for (int i = tid; i < 2048; i += 1024) {
    u32 nxt = (i + 1 < 2048) ? hist[i + 1] : 0;
    if (hist[i] >= need1 && nxt < need1) { sb = (u32)i; sneed = need1 - nxt; }
  }
  __syncthreads();
  u32 p2 = (b1 << 11) | sb, need2 = sneed;
  __syncthreads();

  if (tid < 1024) hist[tid] = 0;
  __syncthreads();
  for (int s = tid; s < S_; s += 1024)
    if ((keys[s] >> 10) == p2) atomicAdd(&hist[keys[s] & 1023u], 1u);
  __syncthreads();
  suffix_scan(hist, 1024, tid);
  for (int i = tid; i < 1024; i += 1024) {
    u32 nxt = (i + 1 < 1024) ? hist[i + 1] : 0;
    if (hist[i] >= need2 && nxt < need2) { sb = (u32)i; sneed = need2 - nxt; }
  }
  __syncthreads();
  u32 T = (p2 << 10) | sb;
  u32 needT = sneed;

  for (int s = tid; s < S_; s += 1024) {
    if (keys[s] > T) {
      u32 p = atomicAdd(&scnt, 1u);
      idx[be * TK_ + p] = s;
      wts[be * TK_ + p] = __builtin_bit_cast(float, keys[s]);
    }
  }
  u32 myc = 0;
#pragma unroll
  for (int j = 0; j < 4; ++j) myc += (keys[tid * 4 + j] == T) ? 1u : 0u;
  tcnt[tid] = myc;
  __syncthreads();
  for (int d = 1; d < 1024; d <<= 1) {
    u32 v = (tid >= d) ? tcnt[tid - d] : 0;
    __syncthreads();
    tcnt[tid] += v;
    __syncthreads();
  }
  u32 rank = tcnt[tid] - myc;
#pragma unroll
  for (int j = 0; j < 4; ++j) {
    int s = tid * 4 + j;
    if (keys[s] == T) {
      if (rank < needT) {
        u32 p = atomicAdd(&scnt, 1u);
        idx[be * TK_ + p] = s;
        wts[be * TK_ + p] = __builtin_bit_cast(float, T);
      }
      rank++;
    }
  }
}

// ---------------- transpose + f32->bf16 (+row-scale, +beta-col-sums) ----------------
__global__ __launch_bounds__(256) void transpose_cvt_kernel(const float* __restrict__ src,
                                                            u16* __restrict__ dst,
                                                            int R, int C,
                                                            const float* __restrict__ scale,
                                                            const float* __restrict__ beta,
                                                            float* __restrict__ Bd) {
  __shared__ float tile[32][33];
  int z = blockIdx.z;
  const float* s = src + (size_t)z * R * C;
  u16* d = dst + (size_t)z * R * C;
  int r0 = blockIdx.x * 32, c0 = blockIdx.y * 32;
  int xx = threadIdx.x & 31, yy = threadIdx.x >> 5;
#pragma unroll
  for (int q = 0; q < 4; ++q)
    tile[yy + q * 8][xx] = s[(size_t)(r0 + yy + q * 8) * C + c0 + xx];
  __syncthreads();
  float sc = scale ? scale[(size_t)z * R + r0 + xx] : 1.f;
#pragma unroll
  for (int q = 0; q < 4; ++q)
    d[(size_t)(c0 + yy + q * 8) * R + r0 + xx] = f2bf(sc * tile[xx][yy + q * 8]);
  if (Bd != nullptr) {
    __syncthreads();
    if (threadIdx.x < 32) {
      float sm = 0.f;
      const float* br = beta + (size_t)z * R + r0;
#pragma unroll
      for (int f = 0; f < 32; ++f) sm += br[f] * tile[f][threadIdx.x];
      unsafeAtomicAdd(&Bd[(size_t)z * C + c0 + threadIdx.x], sm);
    }
  }
}

// ---------------- GEMV: G[e][d] = sum_f W2g[e][d][f] ----------------
__global__ __launch_bounds__(256) void gemv_g_kernel(const u16* __restrict__ W2g,
                                                     float* __restrict__ G) {
  int row = blockIdx.x * 4 + (threadIdx.x >> 6);
  int lane = threadIdx.x & 63;
  const u16* wr = W2g + (size_t)row * F_;
  float s = 0.f;
#pragma unroll
  for (int j = 0; j < 4; ++j) {
    u16x8 v = *(const u16x8*)(wr + (j * 64 + lane) * 8);
#pragma unroll
    for (int t = 0; t < 8; ++t) s += b2f(v[t]);
  }
#pragma unroll
  for (int off = 32; off; off >>= 1) s += __shfl_down(s, off);
  if (lane == 0) G[row] = s;
}

// =====================================================================
// 8-phase 256x256xBK64 K-loop (T2+T3+T4+T5). 8 waves (2m x 4n), wave-tile
// 128x64. LDS: A,B x [2 buf][2 khalf][256 rows x 32 k] = 128 KB.
// Per K-tile t (buf c=t&1): 4 phases (khalf x mhalf), 16 MFMA each.
// Stage exactly 1 half-tile/phase (2 gload16/thread) into the dead region:
//  ph0 -> A.kh1[c^1] (t+1), ph1 -> B.kh1[c^1] (t+1),
//  ph2 -> A.kh0[c]   (t+2), ph3 -> B.kh0[c]   (t+2).
// ONE s_waitcnt vmcnt(4) per K-tile at ph3: queue there is
// [t+1.Akh0, t+1.Bkh0, t+1.Akh1, t+1.Bkh1, t+2.Akh0, t+2.Bkh0] (12 inst)
// -> completes all of t+1, leaves t+2.kh0 (4 inst) in flight. Never 0.
// Swizzle (both sides): LDS slot = kq ^ ((row>>1)&3) -> 2-way (free).
// =====================================================================
#define STG(dst, p0, p1, ko)                                                  \
  gload16((p0) + (ko), (dst) + tid * 8);                                      \
  gload16((p1) + (ko), (dst) + 4096 + tid * 8);

#define PHASE(CB, KH, MH, dst, sp0, sp1, ko, DOVM)                            \
  {                                                                           \
    s16x8 aF[4];                                                              \
    _Pragma("unroll") for (int j = 0; j < 4; ++j)                             \
        aF[j] = *(const s16x8*)&As[CB][KH][aoffs + (MH)*2048 + j * 512];      \
    if ((MH) == 0) {                                                          \
      _Pragma("unroll") for (int g = 0; g < 4; ++g)                           \
          bF[g] = *(const s16x8*)&Bs[CB][KH][boffs + g * 512];                \
    }                                                                         \
    STG(dst, sp0, sp1, ko)                                                    \
    if (DOVM) asm volatile("s_waitcnt vmcnt(4)" ::: "memory");                \
    __builtin_amdgcn_s_barrier();                                             \
    __builtin_amdgcn_s_setprio(1);                                            \
    _Pragma("unroll") for (int j = 0; j < 4; ++j)                             \
        _Pragma("unroll") for (int g = 0; g < 4; ++g)                         \
            acc[(MH)*4 + j][g] = mfma_bf16(aF[j], bF[g], acc[(MH)*4 + j][g]); \
    __builtin_amdgcn_s_setprio(0);                                            \
    __builtin_amdgcn_s_barrier();                                             \
  }

#define KTILE8(CB, t)                                                         \
  {                                                                           \
    int k1 = ((t) + 1 < NT ? (t) + 1 : 0) * 64;                               \
    int k2 = ((t) + 2 < NT ? (t) + 2 : 0) * 64;                               \
    s16x8 bF[4];                                                              \
    PHASE(CB, 0, 0, &As[(CB) ^ 1][1][0], pa0, pa1, k1 + 32, 0)                \
    PHASE(CB, 0, 1, &Bs[(CB) ^ 1][1][0], pb0, pb1, k1 + 32, 0)                \
    PHASE(CB, 1, 0, &As[CB][0][0], pa0, pa1, k2, 0)                           \
    PHASE(CB, 1, 1, &Bs[CB][0][0], pb0, pb1, k2, 1)                           \
  }

__device__ __forceinline__ void kloop8(const u16* pa0, const u16* pa1,
                                       const u16* pb0, const u16* pb1,
                                       u16 (*As)[2][8192], u16 (*Bs)[2][8192],
                                       f32x4 acc[8][4], int NT, int tid,
                                       int aoffs, int boffs) {
  // prologue: tile0 all 4 halves + tile1 kh0 halves (12 inst), vmcnt(4)
  STG(&As[0][0][0], pa0, pa1, 0)
  STG(&Bs[0][0][0], pb0, pb1, 0)
  STG(&As[0][1][0], pa0, pa1, 32)
  STG(&Bs[0][1][0], pb0, pb1, 32)
  STG(&As[1][0][0], pa0, pa1, 64)
  STG(&Bs[1][0][0], pb0, pb1, 64)
  asm volatile("s_waitcnt vmcnt(4)" ::: "memory");
  __builtin_amdgcn_s_barrier();
  for (int t = 0; t < NT; t += 2) {
    KTILE8(0, t)
    KTILE8(1, t + 1)
  }
}

// ---------------- GEMM1: h = gelu(gather(xb) @ W1t^T + b1) + LN stats ----------------
__global__ __launch_bounds__(512, 2) void gemm1_kernel(const u16* __restrict__ xb,
                                                       const u16* __restrict__ W1t,
                                                       const float* __restrict__ b1,
                                                       const int* __restrict__ idx,
                                                       u16* __restrict__ hbuf,
                                                       float2* __restrict__ stats2) {
  int p = blockIdx.x;
  int e = p & 7, slot = p >> 3;              // 0..63
  int tm = slot & 1, tn = (slot >> 1) & 7, bb = slot >> 4;
  int be = bb * 8 + e;
  int t0 = tm * 256, n0 = tn * 256;
  int tid = threadIdx.x, lane = tid & 63, wid = tid >> 6;
  int wm = wid >> 2, wn = wid & 3;
  int cidx = lane & 15, kq = lane >> 4;
  __shared__ u16 As[2][2][8192];
  __shared__ u16 Bs[2][2][8192];
  __shared__ float2 sm[256][4];

  // staging: thread -> rows (tid>>2) and (tid>>2)+128, chunk cc (pre-swizzled)
  int srow = tid >> 2;
  int cc = (tid & 3) ^ ((tid >> 3) & 3);
  int tokA0 = idx[be * TK_ + t0 + srow];
  int tokA1 = idx[be * TK_ + t0 + 128 + srow];
  const u16* bsrc = W1t + (size_t)e * F_ * D_;
  const u16* pa0 = xb + ((size_t)bb * S_ + tokA0) * D_ + cc * 8;
  const u16* pa1 = xb + ((size_t)bb * S_ + tokA1) * D_ + cc * 8;
  const u16* pb0 = bsrc + (size_t)(n0 + srow) * D_ + cc * 8;
  const u16* pb1 = bsrc + (size_t)(n0 + 128 + srow) * D_ + cc * 8;

  // frag read offsets: row*32 + swizzled slot*8
  int sw8 = (kq ^ ((cidx >> 1) & 3)) * 8;
  int aoffs = (wm * 128 + cidx) * 32 + sw8;  // + mh*2048 + j*512
  int boffs = (wn * 64 + cidx) * 32 + sw8;   // + g*512

  f32x4 acc[8][4];
#pragma unroll
  for (int f = 0; f < 8; ++f)
#pragma unroll
    for (int g = 0; g < 4; ++g) acc[f][g] = (f32x4){0.f, 0.f, 0.f, 0.f};

  kloop8(pa0, pa1, pb0, pb1, As, Bs, acc, D_ / 64, tid, aoffs, boffs);

  float bias[4];
#pragma unroll
  for (int g = 0; g < 4; ++g) bias[g] = b1[e * F_ + n0 + wn * 64 + g * 16 + cidx];
  size_t hbase = (size_t)be * TK_ * F_;
#pragma unroll
  for (int f = 0; f < 8; ++f) {
#pragma unroll
    for (int r = 0; r < 4; ++r) {
      int lr = wm * 128 + f * 16 + kq * 4 + r;
      size_t hb = hbase + (size_t)(t0 + lr) * F_ + n0 + wn * 64 + cidx;
      float vs = 0.f, vss = 0.f;
#pragma unroll
      for (int g = 0; g < 4; ++g) {
        float v = acc[f][g][r] + bias[g];
        float gl = 0.5f * v * (1.0f + erff(v * 0.70710678118654752f));
        hbuf[hb + g * 16] = f2bf(gl);
        vs += gl;
        vss += gl * gl;
      }
#pragma unroll
      for (int off = 1; off < 16; off <<= 1) {
        vs += __shfl_xor(vs, off);
        vss += __shfl_xor(vss, off);
      }
      if (cidx == 0) {
        float2 o; o.x = vs; o.y = vss;
        sm[lr][wn] = o;
      }
    }
  }
  __syncthreads();
  if (tid < 256) {
    float2 a0 = sm[tid][0], a1 = sm[tid][1], a2 = sm[tid][2], a3 = sm[tid][3];
    float2 o; o.x = a0.x + a1.x + a2.x + a3.x; o.y = a0.y + a1.y + a2.y + a3.y;
    stats2[((size_t)be * TK_ + t0 + tid) * 8 + tn] = o;
  }
}

// ---------------- GEMM2: out = rstd*(h @ W2g) - rstd*mean*G + Bd + b2 -> scatter ----------------
__global__ __launch_bounds__(512, 2) void gemm2_kernel(const u16* __restrict__ hbuf,
                                                       const u16* __restrict__ W2g,
                                                       const float* __restrict__ b2,
                                                       const int* __restrict__ idx,
                                                       const float* __restrict__ wts,
                                                       float* __restrict__ results,
                                                       const float2* __restrict__ stats2,
                                                       const float* __restrict__ G,
                                                       const float* __restrict__ Bd) {
  int p = blockIdx.x;
  int e = p & 7, slot = p >> 3;              // 0..31
  int tn = slot & 3, tm = (slot >> 2) & 1, bb = slot >> 3;
  int be = bb * 8 + e;
  int t0 = tm * 256, n0 = tn * 256;
  int tid = threadIdx.x, lane = tid & 63, wid = tid >> 6;
  int wm = wid >> 2, wn = wid & 3;
  int cidx = lane & 15, kq = lane >> 4;
  __shared__ u16 As[2][2][8192];
  __shared__ u16 Bs[2][2][8192];
  __shared__ float smean[256];
  __shared__ float srstd[256];

  if (tid < 256) {
    const float2* sp = stats2 + ((size_t)be * TK_ + t0 + tid) * 8;
    float sum = 0.f, ss = 0.f;
#pragma unroll
    for (int j = 0; j < 8; ++j) {
      float2 v = sp[j];
      sum += v.x;
      ss += v.y;
    }
    float mean = sum * (1.f / F_);
    float var = ss * (1.f / F_) - mean * mean;
    smean[tid] = mean;
    srstd[tid] = rsqrtf(var + 1e-5f);
  }
  __syncthreads();

  int srow = tid >> 2;
  int cc = (tid & 3) ^ ((tid >> 3) & 3);
  const u16* asrc = hbuf + (size_t)be * TK_ * F_;
  const u16* bsrc = W2g + (size_t)e * D_ * F_;
  const u16* pa0 = asrc + (size_t)(t0 + srow) * F_ + cc * 8;
  const u16* pa1 = asrc + (size_t)(t0 + 128 + srow) * F_ + cc * 8;
  const u16* pb0 = bsrc + (size_t)(n0 + srow) * F_ + cc * 8;
  const u16* pb1 = bsrc + (size_t)(n0 + 128 + srow) * F_ + cc * 8;

  int sw8 = (kq ^ ((cidx >> 1) & 3)) * 8;
  int aoffs = (wm * 128 + cidx) * 32 + sw8;
  int boffs = (wn * 64 + cidx) * 32 + sw8;

  f32x4 acc[8][4];
#pragma unroll
  for (int f = 0; f < 8; ++f)
#pragma unroll
    for (int g = 0; g < 4; ++g) acc[f][g] = (f32x4){0.f, 0.f, 0.f, 0.f};

  kloop8(pa0, pa1, pb0, pb1, As, Bs, acc, F_ / 64, tid, aoffs, boffs);

  int cb = n0 + wn * 64 + cidx;
  float b2v[4], Gv[4], Bdv[4];
#pragma unroll
  for (int g = 0; g < 4; ++g) {
    b2v[g] = b2[e * D_ + cb + g * 16];
    Gv[g] = G[e * D_ + cb + g * 16];
    Bdv[g] = Bd[e * D_ + cb + g * 16];
  }
#pragma unroll
  for (int f = 0; f < 8; ++f) {
#pragma unroll
    for (int r = 0; r < 4; ++r) {
      int lr = wm * 128 + f * 16 + kq * 4 + r;
      int trow = t0 + lr;
      int tok = idx[be * TK_ + trow];
      float wv = wts[be * TK_ + trow];
      float mean = smean[lr], rstd = srstd[lr];
      float* rrow = results + ((size_t)bb * S_ + tok) * D_ + cb;
#pragma unroll
      for (int g = 0; g < 4; ++g) {
        float out = rstd * acc[f][g][r] - rstd * mean * Gv[g] + Bdv[g] + b2v[g];
        unsafeAtomicAdd(rrow + g * 16, wv * out);
      }
    }
  }
}

extern "C" void kernel_launch(void* const* d_in, const int* in_sizes, int n_in,
                              void* d_out, int out_size, void* d_ws, size_t ws_size,
                              hipStream_t stream) {
  const float* x = (const float*)d_in[0];
  const float* Wr = (const float*)d_in[1];
  const float* W1 = (const float*)d_in[2];
  const float* b1 = (const float*)d_in[3];
  const float* gamma = (const float*)d_in[4];
  const float* beta = (const float*)d_in[5];
  const float* W2 = (const float*)d_in[6];
  const float* b2 = (const float*)d_in[7];

  float* results = (float*)d_out;
  float* logits = results + (size_t)B_ * S_ * D_;

  char* ws = (char*)d_ws;
  const size_t OFF_IDX = 0;                                       // 64 KB
  const size_t OFF_WTS = OFF_IDX + (size_t)B_ * E_ * TK_ * 4;     // 64 KB
  const size_t OFF_ST = OFF_WTS + (size_t)B_ * E_ * TK_ * 4;      // 1 MB stats2
  const size_t OFF_G = OFF_ST + (size_t)B_ * E_ * TK_ * 8 * 8;    // 32 KB
  const size_t OFF_BD = OFF_G + (size_t)E_ * D_ * 4;              // 32 KB
  const size_t OFF_R0 = OFF_BD + (size_t)E_ * D_ * 4;             // 32 MB: xb, then W2g
  const size_t OFF_R1 = OFF_R0 + (size_t)E_ * D_ * F_ * 2;        // 32 MB: W1t
  const size_t OFF_H = OFF_R1 + (size_t)E_ * D_ * F_ * 2;         // 64 MB: hbuf
  const size_t NEED = OFF_H + (size_t)B_ * E_ * TK_ * F_ * 2;
  if (ws_size < NEED) return;

  int* idx = (int*)(ws + OFF_IDX);
  float* wts = (float*)(ws + OFF_WTS);
  float2* stats2 = (float2*)(ws + OFF_ST);
  float* G = (float*)(ws + OFF_G);
  float* Bd = (float*)(ws + OFF_BD);
  u16* xb = (u16*)(ws + OFF_R0);
  u16* W2g = (u16*)(ws + OFF_R0);
  u16* W1t = (u16*)(ws + OFF_R1);
  u16* hbuf = (u16*)(ws + OFF_H);

  rc_kernel<<<dim3(B_ * S_ / 4), 256, 0, stream>>>(x, Wr, logits, xb, results);
  topk_kernel<<<dim3(B_ * E_), 1024, 0, stream>>>(logits, idx, wts);
  transpose_cvt_kernel<<<dim3(D_ / 32, F_ / 32, E_), 256, 0, stream>>>(
      W1, W1t, D_, F_, nullptr, nullptr, nullptr);
  gemm1_kernel<<<dim3(512), 512, 0, stream>>>(xb, W1t, b1, idx, hbuf, stats2);
  // W2g overwrites xb region only after gemm1 completed (in-order stream)
  hipMemsetAsync(Bd, 0, (size_t)E_ * D_ * 4, stream);
  transpose_cvt_kernel<<<dim3(F_ / 32, D_ / 32, E_), 256, 0, stream>>>(
      W2, W2g, F_, D_, gamma, beta, Bd);
  gemv_g_kernel<<<dim3(E_ * D_ / 4), 256, 0, stream>>>(W2g, G);
  gemm2_kernel<<<dim3(256), 512, 0, stream>>>(hbuf, W2g, b2, idx, wts, results,
                                              stats2, G, Bd);
}

// Round 7
// 315.500 us; speedup vs baseline: 1.3225x; 1.3225x over previous
//
#include <hip/hip_runtime.h>
#include <hip/hip_bf16.h>

#define B_ 4
#define S_ 4096
#define D_ 1024
#define E_ 8
#define F_ 2048
#define TK_ 512

typedef unsigned short u16;
typedef unsigned int u32;
typedef u16 u16x4 __attribute__((ext_vector_type(4)));
typedef u16 u16x8 __attribute__((ext_vector_type(8)));
typedef short s16x8 __attribute__((ext_vector_type(8)));
typedef float f32x4 __attribute__((ext_vector_type(4)));

__device__ __forceinline__ u16 f2bf(float f) {
  u32 u = __builtin_bit_cast(u32, f);
  u32 r = (u + 0x7fffu + ((u >> 16) & 1u)) >> 16;
  return (u16)r;
}
__device__ __forceinline__ float b2f(u16 h) {
  return __builtin_bit_cast(float, ((u32)h) << 16);
}
__device__ __forceinline__ void gload16(const u16* g, const u16* l) {
  __builtin_amdgcn_global_load_lds((const __attribute__((address_space(1))) void*)g,
                                   (__attribute__((address_space(3))) void*)l, 16, 0, 0);
}
__device__ __forceinline__ f32x4 mfma_bf16(s16x8 a, s16x8 b, f32x4 c) {
  return __builtin_amdgcn_mfma_f32_16x16x32_bf16(a, b, c, 0, 0, 0);
}
// tanh-approx GELU (JAX approximate=True form), ~6 VALU ops vs ~20 for erff.
__device__ __forceinline__ float gelu_t(float v) {
  float t = v * (1.5957691216f + 0.0713548162726f * v * v);
  return v / (1.f + __expf(-t));
}

// ---------------- fused: router logits+probs + x->bf16 + zero(results) ----------------
__global__ __launch_bounds__(256) void rc_kernel(const float* __restrict__ x,
                                                 const float* __restrict__ Wr,
                                                 float* __restrict__ logits,
                                                 float* __restrict__ probs,
                                                 u16* __restrict__ xb,
                                                 float* __restrict__ results) {
  __shared__ float wr[D_ * E_];
  for (int i = threadIdx.x; i < D_ * E_; i += 256) wr[i] = Wr[i];
  __syncthreads();
  int lane = threadIdx.x & 63;
  int wid = threadIdx.x >> 6;
  int token = blockIdx.x * 4 + wid;
  const float* xr = x + (size_t)token * D_;
  u16* xo = xb + (size_t)token * D_;
  float* ro = results + (size_t)token * D_;
  float acc[E_];
#pragma unroll
  for (int e = 0; e < E_; ++e) acc[e] = 0.f;
#pragma unroll
  for (int q = 0; q < 4; ++q) {
    int d0 = q * 256 + lane * 4;
    float4 v = *(const float4*)(xr + d0);
    u16x4 st;
    st[0] = f2bf(v.x); st[1] = f2bf(v.y); st[2] = f2bf(v.z); st[3] = f2bf(v.w);
    *(u16x4*)(xo + d0) = st;
    *(float4*)(ro + d0) = make_float4(0.f, 0.f, 0.f, 0.f);
    float xv[4] = {v.x, v.y, v.z, v.w};
    const float* w0 = &wr[d0 * E_];
#pragma unroll
    for (int j = 0; j < 4; ++j) {
#pragma unroll
      for (int e = 0; e < E_; ++e) acc[e] += xv[j] * w0[j * E_ + e];
    }
  }
#pragma unroll
  for (int e = 0; e < E_; ++e) {
#pragma unroll
    for (int off = 32; off; off >>= 1) acc[e] += __shfl_down(acc[e], off);
  }
  if (lane == 0) {
    float4 o0 = make_float4(acc[0], acc[1], acc[2], acc[3]);
    float4 o1 = make_float4(acc[4], acc[5], acc[6], acc[7]);
    *(float4*)(logits + (size_t)token * E_) = o0;
    *(float4*)(logits + (size_t)token * E_ + 4) = o1;
    float mx = acc[0];
#pragma unroll
    for (int t = 1; t < 8; ++t) mx = fmaxf(mx, acc[t]);
    float sum = 0.f;
    float pe[8];
#pragma unroll
    for (int t = 0; t < 8; ++t) { pe[t] = expf(acc[t] - mx); sum += pe[t]; }
    float inv = 1.f / sum;
    float4 p0 = make_float4(pe[0] * inv, pe[1] * inv, pe[2] * inv, pe[3] * inv);
    float4 p1 = make_float4(pe[4] * inv, pe[5] * inv, pe[6] * inv, pe[7] * inv);
    *(float4*)(probs + (size_t)token * E_) = p0;
    *(float4*)(probs + (size_t)token * E_ + 4) = p1;
  }
}

// ---------------- top-k per (b,e): exact 3-level radix-histogram select ----------------
__device__ __forceinline__ void suffix_scan(u32* h, int n, int tid) {
  for (int d = 1; d < n; d <<= 1) {
    u32 v[2];
    int c = 0;
    for (int i = tid; i < n; i += 1024) v[c++] = (i + d < n) ? h[i + d] : 0;
    __syncthreads();
    c = 0;
    for (int i = tid; i < n; i += 1024) h[i] += v[c++];
    __syncthreads();
  }
}

__global__ __launch_bounds__(1024) void topk_kernel(const float* __restrict__ probs,
                                                    int* __restrict__ idx,
                                                    float* __restrict__ wts) {
  int be = blockIdx.x, b = be >> 3, e = be & 7;
  __shared__ u32 keys[S_];
  __shared__ u32 hist[2048];
  __shared__ u32 tcnt[1024];
  __shared__ u32 sb, sneed, scnt;
  int tid = threadIdx.x;
  const float* pr = probs + (size_t)b * S_ * E_ + e;
  for (int s = tid; s < S_; s += 1024) keys[s] = __builtin_bit_cast(u32, pr[(size_t)s * E_]);
  if (tid == 0) scnt = 0;

  hist[tid] = 0; hist[tid + 1024] = 0;
  __syncthreads();
  for (int s = tid; s < S_; s += 1024) atomicAdd(&hist[keys[s] >> 21], 1u);
  __syncthreads();
  suffix_scan(hist, 2048, tid);
  for (int i = tid; i < 2048; i += 1024) {
    u32 nxt = (i + 1 < 2048) ? hist[i + 1] : 0;
    if (hist[i] >= (u32)TK_ && nxt < (u32)TK_) { sb = (u32)i; sneed = TK_ - nxt; }
  }
  __syncthreads();
  u32 b1 = sb, need1 = sneed;
  __syncthreads();

  hist[tid] = 0; hist[tid + 1024] = 0;
  __syncthreads();
  for (int s = tid; s < S_; s += 1024)
    if ((keys[s] >> 21) == b1) atomicAdd(&hist[(keys[s] >> 10) & 2047u], 1u);
  __syncthreads();
  suffix_scan(hist, 2048, tid);
  for (int i = tid; i < 2048; i += 1024) {
    u32 nxt = (i + 1 < 2048) ? hist[i + 1] : 0;
    if (hist[i] >= need1 && nxt < need1) { sb = (u32)i; sneed = need1 - nxt; }
  }
  __syncthreads();
  u32 p2 = (b1 << 11) | sb, need2 = sneed;
  __syncthreads();

  if (tid < 1024) hist[tid] = 0;
  __syncthreads();
  for (int s = tid; s < S_; s += 1024)
    if ((keys[s] >> 10) == p2) atomicAdd(&hist[keys[s] & 1023u], 1u);
  __syncthreads();
  suffix_scan(hist, 1024, tid);
  for (int i = tid; i < 1024; i += 1024) {
    u32 nxt = (i + 1 < 1024) ? hist[i + 1] : 0;
    if (hist[i] >= need2 && nxt < need2) { sb = (u32)i; sneed = need2 - nxt; }
  }
  __syncthreads();
  u32 T = (p2 << 10) | sb;
  u32 needT = sneed;

  for (int s = tid; s < S_; s += 1024) {
    if (keys[s] > T) {
      u32 p = atomicAdd(&scnt, 1u);
      idx[be * TK_ + p] = s;
      wts[be * TK_ + p] = __builtin_bit_cast(float, keys[s]);
    }
  }
  u32 myc = 0;
#pragma unroll
  for (int j = 0; j < 4; ++j) myc += (keys[tid * 4 + j] == T) ? 1u : 0u;
  tcnt[tid] = myc;
  __syncthreads();
  for (int d = 1; d < 1024; d <<= 1) {
    u32 v = (tid >= d) ? tcnt[tid - d] : 0;
    __syncthreads();
    tcnt[tid] += v;
    __syncthreads();
  }
  u32 rank = tcnt[tid] - myc;
#pragma unroll
  for (int j = 0; j < 4; ++j) {
    int s = tid * 4 + j;
    if (keys[s] == T) {
      if (rank < needT) {
        u32 p = atomicAdd(&scnt, 1u);
        idx[be * TK_ + p] = s;
        wts[be * TK_ + p] = __builtin_bit_cast(float, T);
      }
      rank++;
    }
  }
}

// ---------------- transpose + f32->bf16 (+row-scale, +beta/gamma col-sums) ----------------
__global__ __launch_bounds__(256) void transpose_cvt_kernel(const float* __restrict__ src,
                                                            u16* __restrict__ dst,
                                                            int R, int C,
                                                            const float* __restrict__ scale,
                                                            const float* __restrict__ beta,
                                                            float* __restrict__ Bd,
                                                            float* __restrict__ G) {
  __shared__ float tile[32][33];
  int z = blockIdx.z;
  const float* s = src + (size_t)z * R * C;
  u16* d = dst + (size_t)z * R * C;
  int r0 = blockIdx.x * 32, c0 = blockIdx.y * 32;
  int xx = threadIdx.x & 31, yy = threadIdx.x >> 5;
#pragma unroll
  for (int q = 0; q < 4; ++q)
    tile[yy + q * 8][xx] = s[(size_t)(r0 + yy + q * 8) * C + c0 + xx];
  __syncthreads();
  float sc = scale ? scale[(size_t)z * R + r0 + xx] : 1.f;
#pragma unroll
  for (int q = 0; q < 4; ++q)
    d[(size_t)(c0 + yy + q * 8) * R + r0 + xx] = f2bf(sc * tile[xx][yy + q * 8]);
  if (Bd != nullptr) {
    __syncthreads();
    if (threadIdx.x < 32) {
      float smb = 0.f, smg = 0.f;
      const float* br = beta + (size_t)z * R + r0;
      const float* gr = scale + (size_t)z * R + r0;
#pragma unroll
      for (int f = 0; f < 32; ++f) {
        smb += br[f] * tile[f][threadIdx.x];
        smg += gr[f] * tile[f][threadIdx.x];
      }
      unsafeAtomicAdd(&Bd[(size_t)z * C + c0 + threadIdx.x], smb);
      unsafeAtomicAdd(&G[(size_t)z * C + c0 + threadIdx.x], smg);
    }
  }
}

// =====================================================================
// m97-structure K-loop (verified R4/R5): 128x128 tile, BK=64, 4 waves,
// single-buffer 32KB LDS, cross-block TLP hides the vmcnt(0) drain.
// G4 swizzle slot^=(row&7), both sides. DO NOT restructure (R3/R6 lesson).
// =====================================================================
__device__ __forceinline__ void kloop97(const u16* const pa[4], const u16* const pb[4],
                                        u16* As, u16* Bs, f32x4 acc[4][4], int NT,
                                        int wid, const int aoff[4], const int boff[4],
                                        int sk0, int sk1) {
  int ldst = wid * 512;
  for (int t = 0; t < NT; ++t) {
    int k0 = t * 64;
#pragma unroll
    for (int q = 0; q < 4; ++q) gload16(pa[q] + k0, As + q * 2048 + ldst);
#pragma unroll
    for (int q = 0; q < 4; ++q) gload16(pb[q] + k0, Bs + q * 2048 + ldst);
    asm volatile("s_waitcnt vmcnt(0)" ::: "memory");
    __builtin_amdgcn_s_barrier();
    s16x8 aF[4], bF[4];
#pragma unroll
    for (int kk = 0; kk < 2; ++kk) {
      int sk = kk ? sk1 : sk0;
#pragma unroll
      for (int f = 0; f < 4; ++f) aF[f] = *(const s16x8*)&As[aoff[f] + sk];
#pragma unroll
      for (int g = 0; g < 4; ++g) bF[g] = *(const s16x8*)&Bs[boff[g] + sk];
      __builtin_amdgcn_s_setprio(1);
#pragma unroll
      for (int f = 0; f < 4; ++f)
#pragma unroll
        for (int g = 0; g < 4; ++g) acc[f][g] = mfma_bf16(aF[f], bF[g], acc[f][g]);
      __builtin_amdgcn_s_setprio(0);
    }
    __builtin_amdgcn_s_barrier();
  }
}

// ---------------- GEMM1: h = gelu(gather(xb) @ W1t^T + b1) + per-row LN stats ----------------
__global__ __launch_bounds__(256, 2) void gemm1_kernel(const u16* __restrict__ xb,
                                                       const u16* __restrict__ W1t,
                                                       const float* __restrict__ b1,
                                                       const int* __restrict__ idx,
                                                       u16* __restrict__ hbuf,
                                                       float2* __restrict__ stats2) {
  int p = blockIdx.x;
  int e = p & 7, slot = p >> 3;
  int tm = slot & 3, bb = (slot >> 2) & 3, tn = slot >> 4;
  int be = bb * 8 + e;
  int t0 = tm * 128, n0 = tn * 128;
  int tid = threadIdx.x, lane = tid & 63, wid = tid >> 6;
  int wm = wid >> 1, wn = wid & 1;
  int cidx = lane & 15, kq = lane >> 4;
  __shared__ u16 As[128 * 64];
  __shared__ u16 Bs[128 * 64];
  __shared__ float2 sm[128][2];

  int srow = tid >> 3;
  int kc = (tid & 7) ^ (srow & 7);
  const u16* pa[4];
  const u16* pb[4];
  const u16* bsrc = W1t + (size_t)e * F_ * D_;
#pragma unroll
  for (int q = 0; q < 4; ++q) {
    int tok = idx[be * TK_ + t0 + q * 32 + srow];
    pa[q] = xb + ((size_t)bb * S_ + tok) * D_ + kc * 8;
    pb[q] = bsrc + (size_t)(n0 + q * 32 + srow) * D_ + kc * 8;
  }
  int aoff[4], boff[4];
#pragma unroll
  for (int f = 0; f < 4; ++f) {
    aoff[f] = (wm * 64 + f * 16 + cidx) * 64;
    boff[f] = (wn * 64 + f * 16 + cidx) * 64;
  }
  int sk0 = (kq ^ (cidx & 7)) * 8;
  int sk1 = ((4 + kq) ^ (cidx & 7)) * 8;

  f32x4 acc[4][4];
#pragma unroll
  for (int f = 0; f < 4; ++f)
#pragma unroll
    for (int g = 0; g < 4; ++g) acc[f][g] = (f32x4){0.f, 0.f, 0.f, 0.f};

  kloop97(pa, pb, As, Bs, acc, D_ / 64, wid, aoff, boff, sk0, sk1);

  float bias[4];
#pragma unroll
  for (int g = 0; g < 4; ++g) bias[g] = b1[e * F_ + n0 + wn * 64 + g * 16 + cidx];
  size_t hbase = (size_t)be * TK_ * F_;
#pragma unroll
  for (int f = 0; f < 4; ++f) {
#pragma unroll
    for (int r = 0; r < 4; ++r) {
      int lr = wm * 64 + f * 16 + kq * 4 + r;
      size_t hb = hbase + (size_t)(t0 + lr) * F_ + n0 + wn * 64 + cidx;
      float vs = 0.f, vss = 0.f;
#pragma unroll
      for (int g = 0; g < 4; ++g) {
        float v = acc[f][g][r] + bias[g];
        float gl = gelu_t(v);
        hbuf[hb + g * 16] = f2bf(gl);
        vs += gl;
        vss += gl * gl;
      }
#pragma unroll
      for (int off = 1; off < 16; off <<= 1) {
        vs += __shfl_xor(vs, off);
        vss += __shfl_xor(vss, off);
      }
      if (cidx == 0) {
        float2 o; o.x = vs; o.y = vss;
        sm[lr][wn] = o;
      }
    }
  }
  __syncthreads();
  if (tid < 128) {
    float2 a = sm[tid][0], b = sm[tid][1];
    float2 o; o.x = a.x + b.x; o.y = a.y + b.y;
    stats2[((size_t)be * TK_ + t0 + tid) * 16 + tn] = o;
  }
}

// ---------------- GEMM2: out = rstd*(h @ W2g) - rstd*mean*G + Bd + b2 -> weighted scatter ----------------
__global__ __launch_bounds__(256, 2) void gemm2_kernel(const u16* __restrict__ hbuf,
                                                       const u16* __restrict__ W2g,
                                                       const float* __restrict__ b2,
                                                       const int* __restrict__ idx,
                                                       const float* __restrict__ wts,
                                                       float* __restrict__ results,
                                                       const float2* __restrict__ stats2,
                                                       const float* __restrict__ G,
                                                       const float* __restrict__ Bd) {
  int p = blockIdx.x;
  int e = p & 7, slot = p >> 3;
  int tn = slot & 7, tm = (slot >> 3) & 3, bb = slot >> 5;
  int be = bb * 8 + e;
  int t0 = tm * 128, n0 = tn * 128;
  int tid = threadIdx.x, lane = tid & 63, wid = tid >> 6;
  int wm = wid >> 1, wn = wid & 1;
  int cidx = lane & 15, kq = lane >> 4;
  __shared__ u16 As[128 * 64];
  __shared__ u16 Bs[128 * 64];
  __shared__ float smean[128];
  __shared__ float srstd[128];

  if (tid < 128) {
    const float2* sp = stats2 + ((size_t)be * TK_ + t0 + tid) * 16;
    float sum = 0.f, ss = 0.f;
#pragma unroll
    for (int j = 0; j < 16; ++j) {
      float2 v = sp[j];
      sum += v.x;
      ss += v.y;
    }
    float mean = sum * (1.f / F_);
    float var = ss * (1.f / F_) - mean * mean;
    smean[tid] = mean;
    srstd[tid] = rsqrtf(var + 1e-5f);
  }
  __syncthreads();

  int srow = tid >> 3;
  int kc = (tid & 7) ^ (srow & 7);
  const u16* pa[4];
  const u16* pb[4];
  const u16* asrc = hbuf + (size_t)be * TK_ * F_;
  const u16* bsrc = W2g + (size_t)e * D_ * F_;
#pragma unroll
  for (int q = 0; q < 4; ++q) {
    pa[q] = asrc + (size_t)(t0 + q * 32 + srow) * F_ + kc * 8;
    pb[q] = bsrc + (size_t)(n0 + q * 32 + srow) * F_ + kc * 8;
  }
  int aoff[4], boff[4];
#pragma unroll
  for (int f = 0; f < 4; ++f) {
    aoff[f] = (wm * 64 + f * 16 + cidx) * 64;
    boff[f] = (wn * 64 + f * 16 + cidx) * 64;
  }
  int sk0 = (kq ^ (cidx & 7)) * 8;
  int sk1 = ((4 + kq) ^ (cidx & 7)) * 8;

  f32x4 acc[4][4];
#pragma unroll
  for (int f = 0; f < 4; ++f)
#pragma unroll
    for (int g = 0; g < 4; ++g) acc[f][g] = (f32x4){0.f, 0.f, 0.f, 0.f};

  kloop97(pa, pb, As, Bs, acc, F_ / 64, wid, aoff, boff, sk0, sk1);

  int cb = n0 + wn * 64 + cidx;
  float b2v[4], Gv[4], Bdv[4];
#pragma unroll
  for (int g = 0; g < 4; ++g) {
    b2v[g] = b2[e * D_ + cb + g * 16];
    Gv[g] = G[e * D_ + cb + g * 16];
    Bdv[g] = Bd[e * D_ + cb + g * 16];
  }
#pragma unroll
  for (int f = 0; f < 4; ++f) {
#pragma unroll
    for (int r = 0; r < 4; ++r) {
      int lr = wm * 64 + f * 16 + kq * 4 + r;
      int trow = t0 + lr;
      int tok = idx[be * TK_ + trow];
      float wv = wts[be * TK_ + trow];
      float mean = smean[lr], rstd = srstd[lr];
      float* rrow = results + ((size_t)bb * S_ + tok) * D_ + cb;
#pragma unroll
      for (int g = 0; g < 4; ++g) {
        float out = rstd * acc[f][g][r] - rstd * mean * Gv[g] + Bdv[g] + b2v[g];
        unsafeAtomicAdd(rrow + g * 16, wv * out);
      }
    }
  }
}

extern "C" void kernel_launch(void* const* d_in, const int* in_sizes, int n_in,
                              void* d_out, int out_size, void* d_ws, size_t ws_size,
                              hipStream_t stream) {
  const float* x = (const float*)d_in[0];
  const float* Wr = (const float*)d_in[1];
  const float* W1 = (const float*)d_in[2];
  const float* b1 = (const float*)d_in[3];
  const float* gamma = (const float*)d_in[4];
  const float* beta = (const float*)d_in[5];
  const float* W2 = (const float*)d_in[6];
  const float* b2 = (const float*)d_in[7];

  float* results = (float*)d_out;
  float* logits = results + (size_t)B_ * S_ * D_;

  char* ws = (char*)d_ws;
  const size_t OFF_IDX = 0;                                       // 64 KB
  const size_t OFF_WTS = OFF_IDX + (size_t)B_ * E_ * TK_ * 4;     // 64 KB
  const size_t OFF_ST = OFF_WTS + (size_t)B_ * E_ * TK_ * 4;      // 2 MB stats2
  const size_t OFF_G = OFF_ST + (size_t)B_ * E_ * TK_ * 16 * 8;   // 32 KB
  const size_t OFF_BD = OFF_G + (size_t)E_ * D_ * 4;              // 32 KB (contig w/ G)
  const size_t OFF_P = OFF_BD + (size_t)E_ * D_ * 4;              // 512 KB probs
  const size_t OFF_R0 = OFF_P + (size_t)B_ * S_ * E_ * 4;         // 32 MB: xb, then W2g
  const size_t OFF_R1 = OFF_R0 + (size_t)E_ * D_ * F_ * 2;        // 32 MB: W1t
  const size_t OFF_H = OFF_R1 + (size_t)E_ * D_ * F_ * 2;         // 64 MB: hbuf
  const size_t NEED = OFF_H + (size_t)B_ * E_ * TK_ * F_ * 2;
  if (ws_size < NEED) return;

  int* idx = (int*)(ws + OFF_IDX);
  float* wts = (float*)(ws + OFF_WTS);
  float2* stats2 = (float2*)(ws + OFF_ST);
  float* G = (float*)(ws + OFF_G);
  float* Bd = (float*)(ws + OFF_BD);
  float* probs = (float*)(ws + OFF_P);
  u16* xb = (u16*)(ws + OFF_R0);
  u16* W2g = (u16*)(ws + OFF_R0);
  u16* W1t = (u16*)(ws + OFF_R1);
  u16* hbuf = (u16*)(ws + OFF_H);

  rc_kernel<<<dim3(B_ * S_ / 4), 256, 0, stream>>>(x, Wr, logits, probs, xb, results);
  topk_kernel<<<dim3(B_ * E_), 1024, 0, stream>>>(probs, idx, wts);
  transpose_cvt_kernel<<<dim3(D_ / 32, F_ / 32, E_), 256, 0, stream>>>(
      W1, W1t, D_, F_, nullptr, nullptr, nullptr, nullptr);
  gemm1_kernel<<<dim3(2048), 256, 0, stream>>>(xb, W1t, b1, idx, hbuf, stats2);
  // W2g overwrites xb region only after gemm1 completed (in-order stream)
  hipMemsetAsync(G, 0, (size_t)2 * E_ * D_ * 4, stream);  // zeros G and Bd (contiguous)
  transpose_cvt_kernel<<<dim3(F_ / 32, D_ / 32, E_), 256, 0, stream>>>(
      W2, W2g, F_, D_, gamma, beta, Bd, G);
  gemm2_kernel<<<dim3(1024), 256, 0, stream>>>(hbuf, W2g, b2, idx, wts, results,
                                               stats2, G, Bd);
}